// Round 3
// baseline (420.387 us; speedup 1.0000x reference)
//
#include <hip/hip_runtime.h>
#include <stdint.h>

// Causal SDPA B=4,H=16,S=2048,D=64 fp32. Flash-MFMA bf16, round 7.
// Fused single kernel, spill-fixed. v6 post-mortem: WRITE_SIZE 37.9->179MB
// = scratch spill from 32 live fp32 prefetch VGPRs held across the whole
// compute phase. Fix: prefetch fp32 loads issued after the LDS-write
// barrier, packed to bf16 MID-compute (K packed after QK, V packed after
// PV) so only 16 packed regs persist across iterations -- v4's footprint.
// V staging: thread owns key-pair (2k,2k+1) x 8 d-rows, pkbf pairs ->
// 8x ds_write_b32 (conflict-free; half the LDS instrs of v6's b16 scatter).
// Compute/P-LDS/epilogue verbatim v4 (proven 81.7us).

#define SLEN 2048
#define DHEAD 64
#define PADP 72

typedef short bf16x8 __attribute__((ext_vector_type(8)));
typedef float f32x4 __attribute__((ext_vector_type(4)));

__device__ __forceinline__ uint32_t pkbf(float hi, float lo) {
    uint32_t a = __builtin_bit_cast(uint32_t, lo) + 0x8000u;
    uint32_t b = __builtin_bit_cast(uint32_t, hi) + 0x8000u;
    return __builtin_amdgcn_perm(b, a, 0x07060302u);
}
__device__ __forceinline__ int swz(int row, int g) {  // offset in shorts, 64x64 tile
    return row * 64 + ((g ^ (row & 7)) << 3);
}

__global__ __launch_bounds__(256, 4)
void sdpa_fused(const float* __restrict__ Qf, const float* __restrict__ Kf,
                const float* __restrict__ Vf, float* __restrict__ Og) {
    const int n = blockIdx.x;
    const int j = n >> 8, c = n & 255;
    const int head = c & 63;
    const int A  = (c >> 6) + 4 * j;   // 0..15
    const int Bq = 31 - A;             // 16..31

    const size_t hb = (size_t)head * SLEN * DHEAD;
    const float* Qh = Qf + hb;
    const float* Kh = Kf + hb;
    const float* Vh = Vf + hb;
    float* Oh = Og + hb;

    const int tid  = threadIdx.x;
    const int w    = tid >> 6, lane = tid & 63;
    const int cl   = lane & 15, quad = lane >> 4;

    __shared__ unsigned short Kl[64 * 64];       // 8192 B swizzled [key][d]
    __shared__ unsigned short Vt[64 * 64];       // 8192 B swizzled [d][key]
    __shared__ unsigned short Pl[4 * 32 * PADP]; // 18432 B per-wave P [q][key]

    // waves 0,1 -> tile A; waves 2,3 -> tile B (balanced: 33 units/block)
    const int qw = ((w < 2) ? A * 64 : Bq * 64) + (w & 1) * 32;
    unsigned short* Plw = Pl + w * 32 * PADP;

    // Q fragments from fp32 global (once per block)
    bf16x8 qf[2][2];
#pragma unroll
    for (int m = 0; m < 2; ++m)
#pragma unroll
        for (int h = 0; h < 2; ++h) {
            const float* src = Qh + (size_t)(qw + m * 16 + cl) * DHEAD + h * 32 + quad * 8;
            float4 a = *(const float4*)src;
            float4 b = *(const float4*)(src + 4);
            uint4 u;
            u.x = pkbf(a.y, a.x); u.y = pkbf(a.w, a.z);
            u.z = pkbf(b.y, b.x); u.w = pkbf(b.w, b.z);
            qf[m][h] = __builtin_bit_cast(bf16x8, u);
        }

    f32x4 o[2][4];
#pragma unroll
    for (int m = 0; m < 2; ++m)
#pragma unroll
        for (int d = 0; d < 4; ++d) o[m][d] = (f32x4){0.f, 0.f, 0.f, 0.f};
    float ls[2] = {0.f, 0.f};
    const float SCL = 0.18033688f;   // (1/8) * log2(e)

    // --- K staging: rows srow0, srow0+32, 8 floats at col sg0*8 (coalesced) ---
    const int srow0 = tid >> 3, sg0 = tid & 7;
    const int srow1 = srow0 + 32;
    const int lo0 = swz(srow0, sg0), lo1 = swz(srow1, sg0);
    const size_t kF0 = (size_t)srow0 * DHEAD + sg0 * 8;
    const size_t kF1 = (size_t)srow1 * DHEAD + sg0 * 8;

    // --- V staging (transposed): thread owns keys (2*vkp, 2*vkp+1) x 8 d-rows ---
    const int vkp = tid & 31, vdb = tid >> 5;          // key-pair, d-block
    const size_t vF0 = (size_t)(2 * vkp) * DHEAD + vdb * 8;   // key 2kp
    const size_t vF1 = vF0 + DHEAD;                           // key 2kp+1
    // LDS write offsets (shorts): row r=vdb*8+d, col-pair vkp within swizzled granule
    const int vg = vkp >> 2, vo2 = (vkp & 3) * 2;

    const int ntiles = Bq + 1;

    // persistent packed prefetch (16 VGPRs, v4 footprint)
    uint4 kp0, kp1;
    uint32_t vp[8];

    {   // prologue: load + pack tile 0 (latency exposed once)
        float4 kA = *(const float4*)(Kh + kF0), kB = *(const float4*)(Kh + kF0 + 4);
        float4 kC = *(const float4*)(Kh + kF1), kD = *(const float4*)(Kh + kF1 + 4);
        float4 vA = *(const float4*)(Vh + vF0), vB = *(const float4*)(Vh + vF0 + 4);
        float4 vC = *(const float4*)(Vh + vF1), vD = *(const float4*)(Vh + vF1 + 4);
        kp0.x = pkbf(kA.y, kA.x); kp0.y = pkbf(kA.w, kA.z);
        kp0.z = pkbf(kB.y, kB.x); kp0.w = pkbf(kB.w, kB.z);
        kp1.x = pkbf(kC.y, kC.x); kp1.y = pkbf(kC.w, kC.z);
        kp1.z = pkbf(kD.y, kD.x); kp1.w = pkbf(kD.w, kD.z);
        vp[0] = pkbf(vC.x, vA.x); vp[1] = pkbf(vC.y, vA.y);
        vp[2] = pkbf(vC.z, vA.z); vp[3] = pkbf(vC.w, vA.w);
        vp[4] = pkbf(vD.x, vB.x); vp[5] = pkbf(vD.y, vB.y);
        vp[6] = pkbf(vD.z, vB.z); vp[7] = pkbf(vD.w, vB.w);
    }

    for (int t = 0; t < ntiles; ++t) {
        const int k0 = t * 64;
        __syncthreads();                      // prior tile's readers done
        *(uint4*)(Kl + lo0) = kp0;
        *(uint4*)(Kl + lo1) = kp1;
#pragma unroll
        for (int d = 0; d < 8; ++d)
            *(uint32_t*)(Vt + (vdb * 8 + d) * 64 + ((vg ^ d) << 3) + vo2) = vp[d];
        __syncthreads();

        const bool more = (t + 1 < ntiles);
        float4 kA, kB, kC, kD, vA, vB, vC, vD;
        if (more) {                           // issue next-tile fp32 loads
            const size_t adv = (size_t)(k0 + 64) * DHEAD;
            kA = *(const float4*)(Kh + kF0 + adv); kB = *(const float4*)(Kh + kF0 + adv + 4);
            kC = *(const float4*)(Kh + kF1 + adv); kD = *(const float4*)(Kh + kF1 + adv + 4);
            vA = *(const float4*)(Vh + vF0 + adv); vB = *(const float4*)(Vh + vF0 + adv + 4);
            vC = *(const float4*)(Vh + vF1 + adv); vD = *(const float4*)(Vh + vF1 + adv + 4);
        }
        const bool active = (k0 <= qw + 31);
        const bool partial = (k0 + 63 > qw);

        if (active) {
            // S^T = K Q^T ; exp ; packed P^T write
#pragma unroll
            for (int kk = 0; kk < 4; ++kk) {
                bf16x8 kb0 = __builtin_bit_cast(bf16x8, *(const uint4*)(Kl + swz(kk * 16 + cl, quad)));
                bf16x8 kb1 = __builtin_bit_cast(bf16x8, *(const uint4*)(Kl + swz(kk * 16 + cl, 4 + quad)));
                const int krel = kk * 16 + quad * 4;
#pragma unroll
                for (int qq = 0; qq < 2; ++qq) {
                    f32x4 s = (f32x4){0.f, 0.f, 0.f, 0.f};
                    s = __builtin_amdgcn_mfma_f32_16x16x32_bf16(kb0, qf[qq][0], s, 0, 0, 0);
                    s = __builtin_amdgcn_mfma_f32_16x16x32_bf16(kb1, qf[qq][1], s, 0, 0, 0);
                    float p0, p1v, p2, p3;
                    if (partial) {
                        const int qrel = qw - k0 + qq * 16 + cl;
                        p0 = (krel + 0 <= qrel) ? __builtin_amdgcn_exp2f(s[0] * SCL) : 0.f;
                        p1v = (krel + 1 <= qrel) ? __builtin_amdgcn_exp2f(s[1] * SCL) : 0.f;
                        p2 = (krel + 2 <= qrel) ? __builtin_amdgcn_exp2f(s[2] * SCL) : 0.f;
                        p3 = (krel + 3 <= qrel) ? __builtin_amdgcn_exp2f(s[3] * SCL) : 0.f;
                    } else {
                        p0 = __builtin_amdgcn_exp2f(s[0] * SCL);
                        p1v = __builtin_amdgcn_exp2f(s[1] * SCL);
                        p2 = __builtin_amdgcn_exp2f(s[2] * SCL);
                        p3 = __builtin_amdgcn_exp2f(s[3] * SCL);
                    }
                    ls[qq] += (p0 + p1v) + (p2 + p3);
                    uint2 pw;
                    pw.x = pkbf(p1v, p0);
                    pw.y = pkbf(p3, p2);
                    *(uint2*)(Plw + (qq * 16 + cl) * PADP + kk * 16 + quad * 4) = pw;
                }
            }
        }

        if (more) {   // pack K now: K fp32 regs die here (live only through QK)
            kp0.x = pkbf(kA.y, kA.x); kp0.y = pkbf(kA.w, kA.z);
            kp0.z = pkbf(kB.y, kB.x); kp0.w = pkbf(kB.w, kB.z);
            kp1.x = pkbf(kC.y, kC.x); kp1.y = pkbf(kC.w, kC.z);
            kp1.z = pkbf(kD.y, kD.x); kp1.w = pkbf(kD.w, kD.z);
        }

        if (active) {
            // P A-frags (same-wave LDS round trip) + V^T B-frags ; O += P V
            bf16x8 pa[2][2];
#pragma unroll
            for (int m = 0; m < 2; ++m)
#pragma unroll
                for (int h = 0; h < 2; ++h)
                    pa[m][h] = __builtin_bit_cast(bf16x8,
                        *(const uint4*)(Plw + (m * 16 + cl) * PADP + h * 32 + quad * 8));
#pragma unroll
            for (int dd = 0; dd < 4; ++dd) {
                bf16x8 vb0 = __builtin_bit_cast(bf16x8, *(const uint4*)(Vt + swz(dd * 16 + cl, quad)));
                bf16x8 vb1 = __builtin_bit_cast(bf16x8, *(const uint4*)(Vt + swz(dd * 16 + cl, 4 + quad)));
#pragma unroll
                for (int m = 0; m < 2; ++m) {
                    o[m][dd] = __builtin_amdgcn_mfma_f32_16x16x32_bf16(pa[m][0], vb0, o[m][dd], 0, 0, 0);
                    o[m][dd] = __builtin_amdgcn_mfma_f32_16x16x32_bf16(pa[m][1], vb1, o[m][dd], 0, 0, 0);
                }
            }
        }

        if (more) {   // pack V last: V fp32 regs die here
            vp[0] = pkbf(vC.x, vA.x); vp[1] = pkbf(vC.y, vA.y);
            vp[2] = pkbf(vC.z, vA.z); vp[3] = pkbf(vC.w, vA.w);
            vp[4] = pkbf(vD.x, vB.x); vp[5] = pkbf(vD.y, vB.y);
            vp[6] = pkbf(vD.z, vB.z); vp[7] = pkbf(vD.w, vB.w);
        }
    }

    // row-sum: reduce across the 4 quads holding the same q (=cl)
#pragma unroll
    for (int qq = 0; qq < 2; ++qq) {
        float v = ls[qq];
        v += __shfl_xor(v, 16);
        v += __shfl_xor(v, 32);
        ls[qq] = v;
    }

    // normalize + store: O row q = qw + m*16 + quad*4 + r, col = dd*16 + cl
#pragma unroll
    for (int m = 0; m < 2; ++m)
#pragma unroll
        for (int r = 0; r < 4; ++r) {
            const float inv = 1.0f / __shfl(ls[m], quad * 4 + r);
#pragma unroll
            for (int dd = 0; dd < 4; ++dd)
                Oh[(size_t)(qw + m * 16 + quad * 4 + r) * DHEAD + dd * 16 + cl] = o[m][dd][r] * inv;
        }
}

extern "C" void kernel_launch(void* const* d_in, const int* in_sizes, int n_in,
                              void* d_out, int out_size, void* d_ws, size_t ws_size,
                              hipStream_t stream) {
    const float* Q = (const float*)d_in[0];
    const float* K = (const float*)d_in[1];
    const float* V = (const float*)d_in[2];
    float*       O = (float*)d_out;
    (void)d_ws; (void)ws_size;

    sdpa_fused<<<dim3(1024), dim3(256), 0, stream>>>(Q, K, V, O);
}

// Round 4
// 190.222 us; speedup vs baseline: 2.2100x; 2.2100x over previous
//
#include <hip/hip_runtime.h>
#include <stdint.h>

// Causal SDPA B=4,H=16,S=2048,D=64 fp32. Flash-MFMA bf16, round 8.
// RECOVERY: exact round-0 two-kernel structure (proven 81.7us sdpa /
// 196.4 total). Fusion abandoned: fp32 K/V through registers spills
// (VGPR pinned at 64 by AGPR split; v6 +141MB, v7 +420MB HBM scratch).
// Two additive VALU cuts in sdpa only, no sync/register structure change:
//   1. softmax scale folded into Q at pack time (-32 v_mul/iter).
//   2. P-pack via v_cvt_pk_bf16_f32 (1 op/word vs pkbf's 3) (-32 VALU/iter).

#define SLEN 2048
#define DHEAD 64
#define NHEADS 64
#define NELEM (SLEN * DHEAD * NHEADS)   // 8388608 per tensor
#define PADP 72

typedef short bf16x8 __attribute__((ext_vector_type(8)));
typedef float f32x4 __attribute__((ext_vector_type(4)));

__device__ __forceinline__ uint32_t pkbf(float hi, float lo) {
    uint32_t a = __builtin_bit_cast(uint32_t, lo) + 0x8000u;
    uint32_t b = __builtin_bit_cast(uint32_t, hi) + 0x8000u;
    return __builtin_amdgcn_perm(b, a, 0x07060302u);
}
__device__ __forceinline__ unsigned short f2bf(float f) {
    return (unsigned short)((__builtin_bit_cast(uint32_t, f) + 0x8000u) >> 16);
}
__device__ __forceinline__ int swz(int row, int g) {  // offset in shorts, 64x64 tile
    return row * 64 + ((g ^ (row & 7)) << 3);
}

// ---------------- pass 1: K straight, V transposed (identical to round 0) ----------------
__global__ __launch_bounds__(256)
void convert_prep(const float* __restrict__ K, const float* __restrict__ V,
                  unsigned short* __restrict__ Kb, unsigned short* __restrict__ Vtb) {
    __shared__ unsigned short Lt[64 * 264];
    const int b = blockIdx.x, t = threadIdx.x;
    if (b < 4096) {
        const int off = (b * 256 + t) * 8;
        float4 a = *(const float4*)(K + off);
        float4 c = *(const float4*)(K + off + 4);
        uint4 o;
        o.x = pkbf(a.y, a.x); o.y = pkbf(a.w, a.z);
        o.z = pkbf(c.y, c.x); o.w = pkbf(c.w, c.z);
        *(uint4*)(Kb + off) = o;
    } else {
        const int vb2 = b - 4096;
        const int head = vb2 >> 3, kblk = vb2 & 7;
        const float* Vh = V + (size_t)head * (SLEN * DHEAD) + kblk * 256 * DHEAD;
        unsigned short* Vo = Vtb + (size_t)head * (SLEN * DHEAD) + kblk * 256;
#pragma unroll
        for (int i = 0; i < 16; ++i) {
            int idx = t + 256 * i;
            int key = idx >> 4, d4 = idx & 15;
            float4 v = *(const float4*)(Vh + key * DHEAD + d4 * 4);
            Lt[(d4 * 4 + 0) * 264 + key] = f2bf(v.x);
            Lt[(d4 * 4 + 1) * 264 + key] = f2bf(v.y);
            Lt[(d4 * 4 + 2) * 264 + key] = f2bf(v.z);
            Lt[(d4 * 4 + 3) * 264 + key] = f2bf(v.w);
        }
        __syncthreads();
#pragma unroll
        for (int jj = 0; jj < 8; ++jj) {
            int idx = t + 256 * jj;
            int d = idx >> 5, k8 = idx & 31;
            *(uint4*)(Vo + (size_t)d * SLEN + k8 * 8) = *(const uint4*)(Lt + d * 264 + k8 * 8);
        }
    }
}

// ---------------- pass 2: flash attention, balanced pair-blocks ----------------
__global__ __launch_bounds__(256, 4)
void sdpa_mfma(const float* __restrict__ Qf, const unsigned short* __restrict__ Kb,
               const unsigned short* __restrict__ Vtb, float* __restrict__ Og) {
    const int n = blockIdx.x;
    const int j = n >> 8, c = n & 255;
    const int head = c & 63;
    const int A  = (c >> 6) + 4 * j;   // 0..15
    const int Bq = 31 - A;             // 16..31

    const size_t hb = (size_t)head * SLEN * DHEAD;
    const float* Qh = Qf + hb;
    const unsigned short* Kh  = Kb + hb;
    const unsigned short* Vth = Vtb + hb;   // [d][2048]
    float* Oh = Og + hb;

    const int tid  = threadIdx.x;
    const int w    = tid >> 6, lane = tid & 63;
    const int cl   = lane & 15, quad = lane >> 4;

    __shared__ unsigned short Kl[64 * 64];       // 8192 B swizzled [key][d]
    __shared__ unsigned short Vt[64 * 64];       // 8192 B swizzled [d][key]
    __shared__ unsigned short Pl[4 * 32 * PADP]; // 18432 B per-wave P [q][key]

    // waves 0,1 -> tile A; waves 2,3 -> tile B; shared K/V staging stream
    const int qw = ((w < 2) ? A * 64 : Bq * 64) + (w & 1) * 32;
    unsigned short* Plw = Pl + w * 32 * PADP;

    const float SCL = 0.18033688f;   // (1/8) * log2(e), folded into Q

    // Q fragments from fp32 global (once per block), pre-scaled by SCL
    bf16x8 qf[2][2];
#pragma unroll
    for (int m = 0; m < 2; ++m)
#pragma unroll
        for (int h = 0; h < 2; ++h) {
            const float* src = Qh + (size_t)(qw + m * 16 + cl) * DHEAD + h * 32 + quad * 8;
            float4 a = *(const float4*)src;
            float4 b = *(const float4*)(src + 4);
            uint4 u;
            u.x = pkbf(a.y * SCL, a.x * SCL); u.y = pkbf(a.w * SCL, a.z * SCL);
            u.z = pkbf(b.y * SCL, b.x * SCL); u.w = pkbf(b.w * SCL, b.z * SCL);
            qf[m][h] = __builtin_bit_cast(bf16x8, u);
        }

    f32x4 o[2][4];
#pragma unroll
    for (int m = 0; m < 2; ++m)
#pragma unroll
        for (int d = 0; d < 4; ++d) o[m][d] = (f32x4){0.f, 0.f, 0.f, 0.f};
    float ls[2] = {0.f, 0.f};

    // staging: 256 threads x 2 uint4 per tensor (tile = 512 uint4)
    const int p1 = tid + 256;
    const int srow0 = tid >> 3, sg0 = tid & 7;
    const int srow1 = p1 >> 3,  sg1 = p1 & 7;
    const int lo0 = swz(srow0, sg0), lo1 = swz(srow1, sg1);
    const size_t kS0 = (size_t)srow0 * DHEAD + sg0 * 8, kS1 = (size_t)srow1 * DHEAD + sg1 * 8;
    const size_t vS0 = (size_t)srow0 * SLEN + sg0 * 8,  vS1 = (size_t)srow1 * SLEN + sg1 * 8;

    const int ntiles = Bq + 1;
    uint4 kr0 = *(const uint4*)(Kh + kS0), kr1 = *(const uint4*)(Kh + kS1);
    uint4 vr0 = *(const uint4*)(Vth + vS0), vr1 = *(const uint4*)(Vth + vS1);

    for (int t = 0; t < ntiles; ++t) {
        const int k0 = t * 64;
        __syncthreads();                      // prior tile's readers done
        *(uint4*)(Kl + lo0) = kr0; *(uint4*)(Kl + lo1) = kr1;
        *(uint4*)(Vt + lo0) = vr0; *(uint4*)(Vt + lo1) = vr1;
        __syncthreads();
        if (t + 1 < ntiles) {                 // prefetch next tile into regs
            const size_t ko = (size_t)(k0 + 64) * DHEAD;
            kr0 = *(const uint4*)(Kh + kS0 + ko);
            kr1 = *(const uint4*)(Kh + kS1 + ko);
            vr0 = *(const uint4*)(Vth + vS0 + (k0 + 64));
            vr1 = *(const uint4*)(Vth + vS1 + (k0 + 64));
        }
        if (k0 > qw + 31) continue;           // wave-uniform; barriers are at loop top
        const bool partial = (k0 + 63 > qw);

        // S^T = K Q^T ; exp ; packed P^T write
#pragma unroll
        for (int kk = 0; kk < 4; ++kk) {
            bf16x8 kb0 = __builtin_bit_cast(bf16x8, *(const uint4*)(Kl + swz(kk * 16 + cl, quad)));
            bf16x8 kb1 = __builtin_bit_cast(bf16x8, *(const uint4*)(Kl + swz(kk * 16 + cl, 4 + quad)));
            const int krel = kk * 16 + quad * 4;
#pragma unroll
            for (int qq = 0; qq < 2; ++qq) {
                f32x4 s = (f32x4){0.f, 0.f, 0.f, 0.f};
                s = __builtin_amdgcn_mfma_f32_16x16x32_bf16(kb0, qf[qq][0], s, 0, 0, 0);
                s = __builtin_amdgcn_mfma_f32_16x16x32_bf16(kb1, qf[qq][1], s, 0, 0, 0);
                float p0, p1v, p2, p3;
                if (partial) {
                    const int qrel = qw - k0 + qq * 16 + cl;
                    p0 = (krel + 0 <= qrel) ? __builtin_amdgcn_exp2f(s[0]) : 0.f;
                    p1v = (krel + 1 <= qrel) ? __builtin_amdgcn_exp2f(s[1]) : 0.f;
                    p2 = (krel + 2 <= qrel) ? __builtin_amdgcn_exp2f(s[2]) : 0.f;
                    p3 = (krel + 3 <= qrel) ? __builtin_amdgcn_exp2f(s[3]) : 0.f;
                } else {
                    p0 = __builtin_amdgcn_exp2f(s[0]);
                    p1v = __builtin_amdgcn_exp2f(s[1]);
                    p2 = __builtin_amdgcn_exp2f(s[2]);
                    p3 = __builtin_amdgcn_exp2f(s[3]);
                }
                ls[qq] += (p0 + p1v) + (p2 + p3);
                uint2 pw;
                asm("v_cvt_pk_bf16_f32 %0, %1, %2" : "=v"(pw.x) : "v"(p0), "v"(p1v));
                asm("v_cvt_pk_bf16_f32 %0, %1, %2" : "=v"(pw.y) : "v"(p2), "v"(p3));
                *(uint2*)(Plw + (qq * 16 + cl) * PADP + kk * 16 + quad * 4) = pw;
            }
        }

        // P A-frags (same-wave LDS round trip) + V^T B-frags ; O += P V
        bf16x8 pa[2][2];
#pragma unroll
        for (int m = 0; m < 2; ++m)
#pragma unroll
            for (int h = 0; h < 2; ++h)
                pa[m][h] = __builtin_bit_cast(bf16x8,
                    *(const uint4*)(Plw + (m * 16 + cl) * PADP + h * 32 + quad * 8));
#pragma unroll
        for (int dd = 0; dd < 4; ++dd) {
            bf16x8 vb0 = __builtin_bit_cast(bf16x8, *(const uint4*)(Vt + swz(dd * 16 + cl, quad)));
            bf16x8 vb1 = __builtin_bit_cast(bf16x8, *(const uint4*)(Vt + swz(dd * 16 + cl, 4 + quad)));
#pragma unroll
            for (int m = 0; m < 2; ++m) {
                o[m][dd] = __builtin_amdgcn_mfma_f32_16x16x32_bf16(pa[m][0], vb0, o[m][dd], 0, 0, 0);
                o[m][dd] = __builtin_amdgcn_mfma_f32_16x16x32_bf16(pa[m][1], vb1, o[m][dd], 0, 0, 0);
            }
        }
    }

    // row-sum: reduce across the 4 quads holding the same q (=cl)
#pragma unroll
    for (int qq = 0; qq < 2; ++qq) {
        float v = ls[qq];
        v += __shfl_xor(v, 16);
        v += __shfl_xor(v, 32);
        ls[qq] = v;
    }

    // normalize + store: O row q = qw + m*16 + quad*4 + r, col = dd*16 + cl
#pragma unroll
    for (int m = 0; m < 2; ++m)
#pragma unroll
        for (int r = 0; r < 4; ++r) {
            const float inv = 1.0f / __shfl(ls[m], quad * 4 + r);
#pragma unroll
            for (int dd = 0; dd < 4; ++dd)
                Oh[(size_t)(qw + m * 16 + quad * 4 + r) * DHEAD + dd * 16 + cl] = o[m][dd][r] * inv;
        }
}

extern "C" void kernel_launch(void* const* d_in, const int* in_sizes, int n_in,
                              void* d_out, int out_size, void* d_ws, size_t ws_size,
                              hipStream_t stream) {
    const float* Q = (const float*)d_in[0];
    const float* K = (const float*)d_in[1];
    const float* V = (const float*)d_in[2];
    float*       O = (float*)d_out;

    unsigned short* Kbf  = (unsigned short*)d_ws;
    unsigned short* Vtbf = Kbf + NELEM;

    convert_prep<<<dim3(4096 + 512), dim3(256), 0, stream>>>(K, V, Kbf, Vtbf);
    sdpa_mfma<<<dim3(1024), dim3(256), 0, stream>>>(Q, Kbf, Vtbf, O);
}